// Round 14
// baseline (68.970 us; speedup 1.0000x reference)
//
#include <hip/hip_runtime.h>

#define H_IMG 128
#define W_IMG 48
#define CIN   64
#define DM    32
#define NH    8
#define NPIX  6144
#define WPAD  50
#define HPAD  130

// 0.5 (dh^-0.5) * log2(e): folded into wq/bq at convert time
#define Q_SCALE 0.7213475204444817f

typedef _Float16 half4 __attribute__((ext_vector_type(4)));
typedef __fp16   fp16x2 __attribute__((ext_vector_type(2)));
typedef float    f32x4 __attribute__((ext_vector_type(4)));

__device__ __forceinline__ float fexp2(float x) { return __builtin_amdgcn_exp2f(x); }

__device__ __forceinline__ half4 exp_pack(f32x4 s) {
    fp16x2 lo = __builtin_amdgcn_cvt_pkrtz(fexp2(s[0]), fexp2(s[1]));
    fp16x2 hi = __builtin_amdgcn_cvt_pkrtz(fexp2(s[2]), fexp2(s[3]));
    half4 p;
    p[0] = (_Float16)lo[0]; p[1] = (_Float16)lo[1];
    p[2] = (_Float16)hi[0]; p[3] = (_Float16)hi[1];
    return p;
}

// ---------------------------------------------------------------------------
// K0: setup, fully parallel — ONE load + ONE store per thread.
// u ranges: [0,104000) xpad f32->f16 (zero border) | [104000,156000) attpad=0
// | [156000,168288) vT ones plane | [168288,223584) whT | [223584,242016) whoT
// ---------------------------------------------------------------------------
__global__ __launch_bounds__(256) void setup_kernel(
    const float* __restrict__ x,
    const float* __restrict__ wq, const float* __restrict__ wk,
    const float* __restrict__ wv, const float* __restrict__ wo,
    _Float16* __restrict__ xpad, _Float16* __restrict__ vT,
    _Float16* __restrict__ attpad,
    _Float16* __restrict__ whT, _Float16* __restrict__ whoT)
{
    const int u = blockIdx.x * 256 + threadIdx.x;

    if (u < 104000) {                       // xpad: one float4 chunk per thread
        const int pp = u >> 4, j = u & 15;
        const int py = pp / WPAD, px = pp % WPAD;
        half4* dst = reinterpret_cast<half4*>(xpad + (size_t)pp * CIN) + j;
        if (py >= 1 && py <= H_IMG && px >= 1 && px <= W_IMG) {
            const float4 v = *reinterpret_cast<const float4*>(
                x + ((size_t)(py - 1) * W_IMG + (px - 1)) * CIN + j * 4);
            half4 hv = { (_Float16)v.x, (_Float16)v.y, (_Float16)v.z, (_Float16)v.w };
            *dst = hv;
        } else {
            const half4 z = {};
            *dst = z;
        }
    } else if (u < 156000) {                // attpad zero: one half4 per thread
        const int t = u - 104000;           // 52000 = 6500 px * 8 chunks
        const half4 z = {};
        reinterpret_cast<half4*>(attpad)[t] = z;
    } else if (u < 168288) {                // vT ones planes: one half4 per thread
        const int t = u - 156000;           // 12288 = 8 h * 1536
        const int h = t / 1536, i = t % 1536;
        half4 ones = { (_Float16)1.0f, (_Float16)1.0f, (_Float16)1.0f, (_Float16)1.0f };
        reinterpret_cast<half4*>(vT + (size_t)(h * 5 + 4) * NPIX)[i] = ones;
    } else if (u < 223584) {                // whT: one element per thread
        const int t = u - 168288;           // 55296
        const int m = t / 18432, rem = t % 18432;
        const int c = rem / 576, kidx = rem % 576;
        const int tap = kidx / 64, ci = kidx % 64;
        const float* w = (m == 0) ? wq : (m == 1) ? wk : wv;
        const float s = (m == 0) ? Q_SCALE : 1.0f;
        whT[t] = (_Float16)(w[(size_t)tap * CIN * DM + (size_t)ci * DM + c] * s);
    } else if (u < 242016) {                // whoT: one element per thread
        const int t = u - 223584;           // 18432
        const int c = t / 288, kidx = t % 288;
        const int tap = kidx / 32, ci = kidx % 32;
        whoT[t] = (_Float16)wo[(size_t)tap * DM * 64 + (size_t)ci * 64 + c];
    }
}

// ---------------------------------------------------------------------------
// K1: QKV conv as MFMA GEMM, dy-split (validated R13).
// ---------------------------------------------------------------------------
__global__ __launch_bounds__(192) void qkv_mfma_kernel(
    const _Float16* __restrict__ xpad,
    const _Float16* __restrict__ whT,
    const float* __restrict__ bq, const float* __restrict__ bk,
    const float* __restrict__ bv,
    half4* __restrict__ qhi, half4* __restrict__ qlo,
    half4* __restrict__ khi, half4* __restrict__ klo,
    _Float16* __restrict__ vT)
{
    __shared__ f32x4 redq[2][64];
    __shared__ _Float16 lt[2][16][20];

    const int pt  = blockIdx.x % 384;
    const int ntm = blockIdx.x / 384;
    const int nt  = ntm % 2;
    const int m   = ntm / 2;
    const int wav = __builtin_amdgcn_readfirstlane(threadIdx.x >> 6);  // = dy
    const int lane = threadIdx.x & 63;
    const int r    = lane & 15;
    const int g16  = lane >> 4;

    const int p  = pt * 16 + r;
    const int y  = p / W_IMG, x0 = p % W_IMG;
    const _Float16* xb = xpad + ((size_t)y * WPAD + x0) * CIN + 4 * g16;

    const int ch = nt * 16 + r;
    const _Float16* wb = whT + ((size_t)(m * 32 + ch)) * 576 + 4 * g16;

    f32x4 acc[4] = {{0.f,0.f,0.f,0.f},{0.f,0.f,0.f,0.f},
                    {0.f,0.f,0.f,0.f},{0.f,0.f,0.f,0.f}};

    const int dy = wav;
    #pragma unroll
    for (int dx = 0; dx < 3; ++dx) {
        const int toff = (dy * WPAD + dx) * CIN;
        const int k0   = (dy * 3 + dx) * 64;
        #pragma unroll
        for (int cb = 0; cb < 4; ++cb) {
            const half4 xa = *reinterpret_cast<const half4*>(xb + toff + cb * 16);
            const half4 wf = *reinterpret_cast<const half4*>(wb + k0 + cb * 16);
            acc[cb] = __builtin_amdgcn_mfma_f32_16x16x16f16(xa, wf, acc[cb], 0, 0, 0);
        }
    }

    f32x4 o = (acc[0] + acc[1]) + (acc[2] + acc[3]);

    if (wav > 0) redq[wav - 1][lane] = o;
    __syncthreads();
    if (wav != 0) return;

    o += redq[0][lane] + redq[1][lane];

    const float* b = (m == 0) ? bq : (m == 1) ? bk : bv;
    const float bias = b[ch] * ((m == 0) ? Q_SCALE : 1.0f);
    #pragma unroll
    for (int j = 0; j < 4; ++j) o[j] += bias;

    if (m == 2) {
        const int plane = (ch >> 2) * 5 + (ch & 3);
        const int pix0 = pt * 16 + 4 * g16;
        half4 hv = { (_Float16)o[0], (_Float16)o[1], (_Float16)o[2], (_Float16)o[3] };
        *reinterpret_cast<half4*>(vT + (size_t)plane * NPIX + pix0) = hv;
    } else {
        #pragma unroll
        for (int j = 0; j < 4; ++j) {
            const float val = o[j];
            const _Float16 hi = (_Float16)val;
            const _Float16 lo = (_Float16)(val - (float)hi);
            lt[0][4 * g16 + j][r] = hi;
            lt[1][4 * g16 + j][r] = lo;
        }
        const int p4 = lane & 15;              // pixel within tile
        const int hh = lane >> 4;              // head within nt-half
        const half4 hv = *reinterpret_cast<const half4*>(&lt[0][p4][hh * 4]);
        const half4 lv = *reinterpret_cast<const half4*>(&lt[1][p4][hh * 4]);
        const int h = nt * 4 + hh;
        const size_t idx = (size_t)h * NPIX + pt * 16 + p4;
        ((half4*)((m == 0) ? qhi : khi))[idx] = hv;
        ((half4*)((m == 0) ? qlo : klo))[idx] = lv;
    }
}

// ---------------------------------------------------------------------------
// K2: fused MFMA local attention + split-K reduce + normalize, SSEG=8,
// with explicit one-row-ahead K/V prefetch (software pipeline).
// Structure identical to validated R13 otherwise.  Last-iter prefetch
// over-reads into adjacent ws buffers (harmless, unused).
// ---------------------------------------------------------------------------
__global__ __launch_bounds__(1024, 8) void attn_mfma_kernel(
    const half4* __restrict__ qhi, const half4* __restrict__ qlo,
    const half4* __restrict__ khi, const half4* __restrict__ klo,
    const _Float16* __restrict__ vT,
    _Float16* __restrict__ attpad)
{
    __shared__ f32x4 red[16][2][64];   // 32 KB

    const int hg  = blockIdx.x / 48;
    const int qq  = blockIdx.x % 48;
    const int h   = hg >> 1, g = hg & 1;
    const int wav = __builtin_amdgcn_readfirstlane(threadIdx.x >> 6);  // 0..15
    const int seg = wav & 7;
    const int u   = wav >> 3;
    const int qt0 = qq * 4 + u * 2;           // tiles qt0, qt0+1
    const int lane = threadIdx.x & 63;
    const int c    = lane & 15;
    const int g16  = lane >> 4;
    const int c0   = g * 16;

    half4 qfA = {}, qfB = {};
    {
        const half4* qsrc = (g16 == 1) ? qlo : qhi;
        const int qa  = qt0 * 16 + c;
        const int qay = qa / 24;
        const int qb  = qa + 16;
        const int qby = qb / 24;
        if (g16 < 3) {
            qfA = qsrc[h * NPIX + qay * W_IMG + g * 24 + (qa - qay * 24)];
            qfB = qsrc[h * NPIX + qby * W_IMG + g * 24 + (qb - qby * 24)];
        }
    }

    const half4* kb = ((g16 == 2) ? klo : khi) + h * NPIX + c;
    const int vplane = (c < 4) ? c : 4;
    const _Float16* vb = vT + (h * 5 + vplane) * NPIX + 4 * g16;

    const f32x4 zc = {0.f, 0.f, 0.f, 0.f};
    f32x4 oA0 = zc, oA1 = zc, oB0 = zc, oB1 = zc;

    int koff = (seg * 16) * W_IMG + c0;
    half4 k0 = kb[koff];
    half4 k1 = kb[koff + 16];
    half4 v0 = *reinterpret_cast<const half4*>(vb + koff);
    half4 v1 = *reinterpret_cast<const half4*>(vb + koff + 16);

    #pragma unroll 4
    for (int r = 0; r < 16; ++r) {
        // prefetch next row (over-reads harmlessly on last iteration)
        const int koff2 = koff + W_IMG;
        const half4 nk0 = kb[koff2];
        const half4 nk1 = kb[koff2 + 16];
        const half4 nv0 = *reinterpret_cast<const half4*>(vb + koff2);
        const half4 nv1 = *reinterpret_cast<const half4*>(vb + koff2 + 16);

        const f32x4 sA0 = __builtin_amdgcn_mfma_f32_16x16x16f16(k0, qfA, zc, 0, 0, 0);
        const f32x4 sA1 = __builtin_amdgcn_mfma_f32_16x16x16f16(k1, qfA, zc, 0, 0, 0);
        const f32x4 sB0 = __builtin_amdgcn_mfma_f32_16x16x16f16(k0, qfB, zc, 0, 0, 0);
        const f32x4 sB1 = __builtin_amdgcn_mfma_f32_16x16x16f16(k1, qfB, zc, 0, 0, 0);

        const half4 pA0 = exp_pack(sA0);
        const half4 pA1 = exp_pack(sA1);
        const half4 pB0 = exp_pack(sB0);
        const half4 pB1 = exp_pack(sB1);

        oA0 = __builtin_amdgcn_mfma_f32_16x16x16f16(pA0, v0, oA0, 0, 0, 0);
        oA1 = __builtin_amdgcn_mfma_f32_16x16x16f16(pA1, v1, oA1, 0, 0, 0);
        oB0 = __builtin_amdgcn_mfma_f32_16x16x16f16(pB0, v0, oB0, 0, 0, 0);
        oB1 = __builtin_amdgcn_mfma_f32_16x16x16f16(pB1, v1, oB1, 0, 0, 0);

        koff = koff2;
        k0 = nk0; k1 = nk1; v0 = nv0; v1 = nv1;
    }

    red[wav][0][lane] = oA0 + oA1;
    red[wav][1][lane] = oB0 + oB1;
    __syncthreads();

    if (wav < 4) {
        const int u2  = wav >> 1;              // pair group
        const int t01 = wav & 1;               // tile within pair
        f32x4 o = red[u2 * 8 + 0][t01][lane];
        #pragma unroll
        for (int s = 1; s < 8; ++s)
            o += red[u2 * 8 + s][t01][lane];

        const int baddr = (g16 * 16 + 4) << 2; // ssum column lane, in bytes
        f32x4 on;
        #pragma unroll
        for (int r = 0; r < 4; ++r) {
            const float ss = __int_as_float(
                __builtin_amdgcn_ds_bpermute(baddr, __float_as_int(o[r])));
            on[r] = o[r] * __builtin_amdgcn_rcpf(ss);
        }

        if (c < 4) {
            const int qt = qq * 4 + u2 * 2 + t01;
            #pragma unroll
            for (int r = 0; r < 4; ++r) {
                const int q  = qt * 16 + 4 * g16 + r;
                const int qy = q / 24;
                const int qx = g * 24 + (q - qy * 24);
                attpad[((size_t)(qy + 1) * WPAD + qx + 1) * DM + h * 4 + c] =
                    (_Float16)on[r];
            }
        }
    }
}

// ---------------------------------------------------------------------------
// K3: output conv as MFMA GEMM, dy-split (validated R13).
// ---------------------------------------------------------------------------
__global__ __launch_bounds__(192) void out_mfma_kernel(
    const _Float16* __restrict__ attpad,
    const _Float16* __restrict__ whoT,
    float* __restrict__ out)
{
    __shared__ f32x4 redo[2][64];

    const int pt  = blockIdx.x % 384;
    const int nt  = blockIdx.x / 384;        // 0..3
    const int wav = __builtin_amdgcn_readfirstlane(threadIdx.x >> 6);  // = dy
    const int lane = threadIdx.x & 63;
    const int r    = lane & 15;
    const int g16  = lane >> 4;

    const int p  = pt * 16 + r;
    const int y  = p / W_IMG, x0 = p % W_IMG;
    const _Float16* ab = attpad + ((size_t)y * WPAD + x0) * DM + 4 * g16;

    const int ch = nt * 16 + r;
    const _Float16* wb = whoT + (size_t)ch * 288 + 4 * g16;

    f32x4 a0 = {0.f, 0.f, 0.f, 0.f}, a1 = {0.f, 0.f, 0.f, 0.f};

    const int dy = wav;
    #pragma unroll
    for (int dx = 0; dx < 3; ++dx) {
        const int toff = (dy * WPAD + dx) * DM;
        const int k0   = (dy * 3 + dx) * 32;
        const half4 xa0 = *reinterpret_cast<const half4*>(ab + toff);
        const half4 wf0 = *reinterpret_cast<const half4*>(wb + k0);
        a0 = __builtin_amdgcn_mfma_f32_16x16x16f16(xa0, wf0, a0, 0, 0, 0);
        const half4 xa1 = *reinterpret_cast<const half4*>(ab + toff + 16);
        const half4 wf1 = *reinterpret_cast<const half4*>(wb + k0 + 16);
        a1 = __builtin_amdgcn_mfma_f32_16x16x16f16(xa1, wf1, a1, 0, 0, 0);
    }

    f32x4 o = a0 + a1;
    if (wav > 0) redo[wav - 1][lane] = o;
    __syncthreads();
    if (wav != 0) return;

    o += redo[0][lane] + redo[1][lane];

    const int pix0 = pt * 16 + 4 * g16;
    #pragma unroll
    for (int j = 0; j < 4; ++j)
        out[(size_t)(pix0 + j) * 64 + nt * 16 + r] = o[j];
}

// ---------------------------------------------------------------------------
extern "C" void kernel_launch(void* const* d_in, const int* in_sizes, int n_in,
                              void* d_out, int out_size, void* d_ws, size_t ws_size,
                              hipStream_t stream)
{
    const float* x  = (const float*)d_in[0];
    const float* wq = (const float*)d_in[1];
    const float* bq = (const float*)d_in[2];
    const float* wk = (const float*)d_in[3];
    const float* bk = (const float*)d_in[4];
    const float* wv = (const float*)d_in[5];
    const float* bv = (const float*)d_in[6];
    const float* wo = (const float*)d_in[7];
    float* out = (float*)d_out;

    // workspace layout (bytes)
    char* base = (char*)d_ws;
    half4*    qhi    = (half4*)(base + 0);          //  393216
    half4*    qlo    = (half4*)(base + 393216);
    half4*    khi    = (half4*)(base + 786432);
    half4*    klo    = (half4*)(base + 1179648);
    _Float16* vT     = (_Float16*)(base + 1572864); //  491520 (8h x 5 planes)
    _Float16* xpad   = (_Float16*)(base + 2064384); //  832000 -> 2896384
    _Float16* attpad = (_Float16*)(base + 2896384); //  416000 -> 3312384
    _Float16* whT    = (_Float16*)(base + 3312384); //  110592 -> 3422976
    _Float16* whoT   = (_Float16*)(base + 3422976); //   36864 -> 3459840

    hipLaunchKernelGGL(setup_kernel, dim3(946), dim3(256), 0, stream,
                       x, wq, wk, wv, wo, xpad, vT, attpad, whT, whoT);

    hipLaunchKernelGGL(qkv_mfma_kernel, dim3(2304), dim3(192), 0, stream,
                       xpad, whT, bq, bk, bv, qhi, qlo, khi, klo, vT);

    hipLaunchKernelGGL(attn_mfma_kernel, dim3(16 * 48), dim3(1024), 0, stream,
                       qhi, qlo, khi, klo, vT, attpad);

    hipLaunchKernelGGL(out_mfma_kernel, dim3(4 * 384), dim3(192), 0, stream,
                       attpad, whoT, out);
}